// Round 3
// baseline (74.260 us; speedup 1.0000x reference)
//
#include <hip/hip_runtime.h>
#include <math.h>

// Problem constants (from reference): TS=4, BS=16, N=2048, F=64
#define TS 4
#define BS 16
#define NN 2048
#define FF 64
#define NEGV -9.0e15f

// One block per (t, b) pair: 4*16 = 64 blocks, 256 threads each.
// Computes y = softmax-weighted mean of x over the masked attention row N-1,
// then out[b,t,f] = elu(y * W[t,f]).
__global__ __launch_bounds__(256) void gat_last_row_kernel(
    const float* __restrict__ x,    // (TS, BS*NN)
    const float* __restrict__ adj,  // (NN, NN)
    const float* __restrict__ W,    // (TS, FF)
    const float* __restrict__ a,    // (TS, 2*FF)
    float* __restrict__ out)        // (BS, TS, FF)
{
    const int blk = blockIdx.x;   // 0..63
    const int t   = blk >> 4;     // /BS
    const int b   = blk & 15;     // %BS
    const int tid = threadIdx.x;

    // A1 = W_t . a1, A2 = W_t . a2 — tiny, computed redundantly per thread
    const float* Wt = W + t * FF;
    const float* at = a + t * 2 * FF;
    float A1 = 0.f, A2 = 0.f;
#pragma unroll
    for (int f = 0; f < FF; ++f) {
        float w = Wt[f];
        A1 += w * at[f];
        A2 += w * at[FF + f];
    }

    const float* xb = x + (size_t)t * (BS * NN) + (size_t)b * NN;
    const float  x_last = xb[NN - 1];
    const float  s1 = x_last * A1;
    const float* adjrow = adj + (size_t)(NN - 1) * NN;

    // Online softmax state over att_j, accumulating weighted x as well.
    float m = -INFINITY, l = 0.f, y = 0.f;

    const float4* x4 = (const float4*)xb;
    const float4* a4 = (const float4*)adjrow;
#pragma unroll
    for (int k = tid; k < NN / 4; k += 256) {   // 2 iterations per thread
        float4 xv = x4[k];
        float4 av = a4[k];
#pragma unroll
        for (int u = 0; u < 4; ++u) {
            float xj   = (&xv.x)[u];
            float adjv = (&av.x)[u];
            float s    = s1 + xj * A2;
            // leaky_relu(s)>0 <=> s>0, and equals s there; else masked to NEG
            float att  = (adjv > 0.f && s > 0.f) ? s : NEGV;
            float mn   = fmaxf(m, att);
            float sa   = expf(m - mn);    // m=-inf first iter -> 0, l=0 -> ok
            float pe   = expf(att - mn);
            l = l * sa + pe;
            y = y * sa + pe * xj;
            m = mn;
        }
    }

    // Wave (64-lane) butterfly reduction of (m, l, y) online-softmax state
#pragma unroll
    for (int off = 32; off; off >>= 1) {
        float m2 = __shfl_xor(m, off);
        float l2 = __shfl_xor(l, off);
        float y2 = __shfl_xor(y, off);
        float mn = fmaxf(m, m2);
        float sa = expf(m - mn);
        float sb = expf(m2 - mn);
        l = l * sa + l2 * sb;
        y = y * sa + y2 * sb;
        m = mn;
    }

    // Cross-wave (4 waves) reduction via LDS
    __shared__ float sm[4], sl[4], sy[4];
    __shared__ float yfinal;
    const int wave = tid >> 6;
    const int lane = tid & 63;
    if (lane == 0) { sm[wave] = m; sl[wave] = l; sy[wave] = y; }
    __syncthreads();
    if (tid == 0) {
        float M = sm[0], L = sl[0], Y = sy[0];
#pragma unroll
        for (int wv = 1; wv < 4; ++wv) {
            float mn = fmaxf(M, sm[wv]);
            float sa = expf(M - mn);
            float sb = expf(sm[wv] - mn);
            L = L * sa + sl[wv] * sb;
            Y = Y * sa + sy[wv] * sb;
            M = mn;
        }
        yfinal = Y / L;
    }
    __syncthreads();

    // out[b, t, f] = elu(y * W[t, f])
    if (tid < FF) {
        float v = yfinal * Wt[tid];
        out[(size_t)b * (TS * FF) + t * FF + tid] = (v > 0.f) ? v : expm1f(v);
    }
}

extern "C" void kernel_launch(void* const* d_in, const int* in_sizes, int n_in,
                              void* d_out, int out_size, void* d_ws, size_t ws_size,
                              hipStream_t stream) {
    const float* x   = (const float*)d_in[0];  // (4, 32768, 1)
    const float* adj = (const float*)d_in[1];  // (2048, 2048)
    const float* W   = (const float*)d_in[2];  // (4, 1, 64)
    const float* a   = (const float*)d_in[3];  // (4, 128, 1)
    // d_in[4] = bs scalar (16), hard-coded

    float* out = (float*)d_out;                // 16*4*64 = 4096 floats

    gat_last_row_kernel<<<TS * BS, 256, 0, stream>>>(x, adj, W, a, out);
}

// Round 4
// 71.239 us; speedup vs baseline: 1.0424x; 1.0424x over previous
//
#include <hip/hip_runtime.h>
#include <math.h>

// Problem constants (from reference): TS=4, BS=16, N=2048, F=64
#define TS 4
#define BS 16
#define NN 2048
#define FF 64
#define NEGV -9.0e15f

// One block per (t, b) pair: 4*16 = 64 blocks, 256 threads each.
// out[:, -1, :] only is kept by the reference, and h = x*W is rank-1, so the
// whole GAT layer collapses to a masked softmax-weighted scalar mean y over
// the last adjacency row, then out[b,t,f] = elu(y * W[t,f]).
__global__ __launch_bounds__(256) void gat_last_row_kernel(
    const float* __restrict__ x,    // (TS, BS*NN)
    const float* __restrict__ adj,  // (NN, NN)
    const float* __restrict__ W,    // (TS, FF)
    const float* __restrict__ a,    // (TS, 2*FF)
    float* __restrict__ out)        // (BS, TS, FF)
{
    const int blk  = blockIdx.x;   // 0..63
    const int t    = blk >> 4;     // /BS
    const int b    = blk & 15;     // %BS
    const int tid  = threadIdx.x;
    const int lane = tid & 63;
    const int wave = tid >> 6;

    // A1 = W_t.a1, A2 = W_t.a2 — lane-parallel dot (FF==64==wave size)
    const float* Wt = W + t * FF;
    const float* at = a + t * 2 * FF;
    const float w   = Wt[lane];
    float pa1 = w * at[lane];
    float pa2 = w * at[FF + lane];
#pragma unroll
    for (int off = 32; off; off >>= 1) {
        pa1 += __shfl_xor(pa1, off);
        pa2 += __shfl_xor(pa2, off);
    }
    const float A1 = pa1, A2 = pa2;

    const float* xb = x + (size_t)t * (BS * NN) + (size_t)b * NN;
    const float  s1 = xb[NN - 1] * A1;
    const float* adjrow = adj + (size_t)(NN - 1) * NN;

    // Load this thread's 8 elements into registers (2 float4 each stream)
    const float4* x4 = (const float4*)xb;
    const float4* a4 = (const float4*)adjrow;
    float4 xv0 = x4[tid], xv1 = x4[tid + 256];
    float4 av0 = a4[tid], av1 = a4[tid + 256];

    float xs[8]  = { xv0.x, xv0.y, xv0.z, xv0.w, xv1.x, xv1.y, xv1.z, xv1.w };
    float as[8]  = { av0.x, av0.y, av0.z, av0.w, av1.x, av1.y, av1.z, av1.w };
    float att[8];
#pragma unroll
    for (int u = 0; u < 8; ++u) {
        float s = fmaf(xs[u], A2, s1);
        // leaky_relu(s)>0 <=> s>0, identity on positives; else masked to NEG
        att[u] = (as[u] > 0.f && s > 0.f) ? s : NEGV;
    }

    // Pass 1: block max
    float mloc = fmaxf(fmaxf(fmaxf(att[0], att[1]), fmaxf(att[2], att[3])),
                       fmaxf(fmaxf(att[4], att[5]), fmaxf(att[6], att[7])));
#pragma unroll
    for (int off = 32; off; off >>= 1)
        mloc = fmaxf(mloc, __shfl_xor(mloc, off));

    __shared__ float smax[4];
    if (lane == 0) smax[wave] = mloc;
    __syncthreads();
    const float M = fmaxf(fmaxf(smax[0], smax[1]), fmaxf(smax[2], smax[3]));

    // Pass 2: sums. exp(NEGV - M) flushes to 0 -> masking is automatic;
    // all-masked row -> M=NEGV -> exp(0)=1 each -> uniform mean (matches ref).
    float l = 0.f, y = 0.f;
#pragma unroll
    for (int u = 0; u < 8; ++u) {
        float p = expf(att[u] - M);
        l += p;
        y  = fmaf(p, xs[u], y);
    }
#pragma unroll
    for (int off = 32; off; off >>= 1) {
        l += __shfl_xor(l, off);
        y += __shfl_xor(y, off);
    }

    __shared__ float sl[4], sy[4];
    if (lane == 0) { sl[wave] = l; sy[wave] = y; }
    __syncthreads();

    // Epilogue: out[b, t, f] = elu(y/l * W[t, f]); wave 0 has w = Wt[tid]
    if (tid < FF) {
        float L  = (sl[0] + sl[1]) + (sl[2] + sl[3]);
        float Y  = (sy[0] + sy[1]) + (sy[2] + sy[3]);
        float v  = (Y / L) * w;
        out[(size_t)b * (TS * FF) + t * FF + tid] = (v > 0.f) ? v : expm1f(v);
    }
}

extern "C" void kernel_launch(void* const* d_in, const int* in_sizes, int n_in,
                              void* d_out, int out_size, void* d_ws, size_t ws_size,
                              hipStream_t stream) {
    const float* x   = (const float*)d_in[0];  // (4, 32768, 1)
    const float* adj = (const float*)d_in[1];  // (2048, 2048)
    const float* W   = (const float*)d_in[2];  // (4, 1, 64)
    const float* a   = (const float*)d_in[3];  // (4, 128, 1)
    // d_in[4] = bs scalar (16), hard-coded

    float* out = (float*)d_out;                // (BS, TS, FF) = 4096 floats

    gat_last_row_kernel<<<TS * BS, 256, 0, stream>>>(x, adj, W, a, out);
}